// Round 4
// baseline (133.003 us; speedup 1.0000x reference)
//
#include <hip/hip_runtime.h>
#include <math.h>

// DotProductAttention B=64,S=1024,D=64 fp32, bf16-MFMA flash attention.
// Round 3: pipeline attack. Double-buffered K/V LDS + ONE barrier per
// K-iteration: compute on buf[p] overlaps staging of tile it+1 into buf[1-p]
// and global prefetch of tile it+2. LDS 46 KB -> 3 blocks/CU (768 resident,
// 256 queued -> backfill covers vl-imbalance tail). Q in registers, exp2
// softmax, perm-truncation bf16 packs, batch-major XCD swizzle.

#define BATCH 64
#define SEQ   1024
#define DIM   64
#define BQ    64           // queries per block (4 waves x 16)
#define BC    64           // keys per iteration
#define NKT   (SEQ / BC)   // 16
#define LSTR  72           // LDS row stride in bf16 (144 B = 36 dwords === 4 mod 32)
#define QSCALE 0.18033688011112442f   // 0.125 * log2(e)
#define MASKED -1.0e6f

typedef __attribute__((ext_vector_type(8))) short bf16x8;
typedef __attribute__((ext_vector_type(4))) float f32x4;

__device__ __forceinline__ uint pack2_trunc(float lo, float hi) {
    // [bf16(hi) : bf16(lo)] by byte-select (truncation) — one v_perm_b32
    return __builtin_amdgcn_perm(__float_as_uint(hi), __float_as_uint(lo), 0x07060302);
}
__device__ __forceinline__ ushort f2bf_rne(float x) {
    uint u = __float_as_uint(x);
    return (ushort)((u + 0x7fffu + ((u >> 16) & 1u)) >> 16);
}

__global__ __launch_bounds__(256, 3) void attn_mfma_flash3(
    const float* __restrict__ q, const float* __restrict__ k,
    const float* __restrict__ v, const int* __restrict__ valid_lens,
    float* __restrict__ out)
{
    __shared__ ushort Ks[2][BC * LSTR];   // [buf][key][d]
    __shared__ ushort Vt[2][DIM * LSTR];  // [buf][d][key]
    __shared__ ushort Ps[BQ * LSTR];      // [query][key], wave-private bands

    const int t    = threadIdx.x;
    const int wave = t >> 6;
    const int wl   = t & 63;
    const int QD   = wl >> 4;          // quad 0..3
    const int li   = wl & 15;          // lane-in-quad 0..15
    // batch-major swizzle: all 16 q-tiles of a batch land on the same XCD
    const int b    = blockIdx.x & 63;
    const int q0   = (blockIdx.x >> 6) * BQ;
    const int vl   = valid_lens[b];

    const size_t boff = (size_t)b * SEQ * DIM;

    // ---- Q fragments straight into registers (B-operand), pre-scaled ----
    bf16x8 qb[2];
    {
        const float* qrow = q + boff + (size_t)(q0 + wave * 16 + li) * DIM + QD * 8;
        #pragma unroll
        for (int kc = 0; kc < 2; kc++) {
            float4 a = *(const float4*)(qrow + kc * 32);
            float4 c = *(const float4*)(qrow + kc * 32 + 4);
            union { bf16x8 v; ushort u[8]; } tmp;
            tmp.u[0] = f2bf_rne(a.x * QSCALE);
            tmp.u[1] = f2bf_rne(a.y * QSCALE);
            tmp.u[2] = f2bf_rne(a.z * QSCALE);
            tmp.u[3] = f2bf_rne(a.w * QSCALE);
            tmp.u[4] = f2bf_rne(c.x * QSCALE);
            tmp.u[5] = f2bf_rne(c.y * QSCALE);
            tmp.u[6] = f2bf_rne(c.z * QSCALE);
            tmp.u[7] = f2bf_rne(c.w * QSCALE);
            qb[kc] = tmp.v;
        }
    }

    const int it_max = (vl == 0) ? NKT : ((vl + BC - 1) >> 6);

    // ---- prefetch registers (one tile in flight) ----
    float4 kf[4];          // K tile: 4 coalesced float4 per thread
    float  vf[2][8];       // V gather: (d = lane, 8 consecutive keys) x 2 slots

    auto load_tile = [&](int it) {
        const float4* kg = (const float4*)(k + boff + (size_t)it * BC * DIM);
        #pragma unroll
        for (int i = 0; i < 4; i++) kf[i] = kg[t + 256 * i];
        const float* vgf = v + boff + (size_t)it * BC * DIM;
        #pragma unroll
        for (int i = 0; i < 2; i++) {
            int slot = t + 256 * i;
            int d = slot & 63, ko = slot >> 6;
            #pragma unroll
            for (int j = 0; j < 8; j++)
                vf[i][j] = vgf[(size_t)(ko * 8 + j) * DIM + d];
        }
    };

    auto stage = [&](int p) {
        #pragma unroll
        for (int i = 0; i < 4; i++) {
            int idx = t + 256 * i;
            int row = idx >> 4, c4 = idx & 15;
            uint2 w;
            w.x = pack2_trunc(kf[i].x, kf[i].y);
            w.y = pack2_trunc(kf[i].z, kf[i].w);
            *(uint2*)&Ks[p][row * LSTR + c4 * 4] = w;
        }
        #pragma unroll
        for (int i = 0; i < 2; i++) {
            int slot = t + 256 * i;
            int d = slot & 63, ko = slot >> 6;
            uint4 w;
            w.x = pack2_trunc(vf[i][0], vf[i][1]);
            w.y = pack2_trunc(vf[i][2], vf[i][3]);
            w.z = pack2_trunc(vf[i][4], vf[i][5]);
            w.w = pack2_trunc(vf[i][6], vf[i][7]);
            *(uint4*)&Vt[p][d * LSTR + ko * 8] = w;   // b128, bank-uniform
        }
    };

    float m_run = -INFINITY, l_run = 0.f;
    f32x4 acc[4];
    #pragma unroll
    for (int dt = 0; dt < 4; dt++) acc[dt] = (f32x4){0.f, 0.f, 0.f, 0.f};

    // prologue: tile 0 staged, tile 1 in registers
    load_tile(0);
    stage(0);
    if (it_max > 1) load_tile(1);
    __syncthreads();

    for (int it = 0; it < it_max; it++) {
        const int p = it & 1;

        // ---- S^T = K x Q^T : rows = keys (QD*4+r), cols = queries (li) ----
        f32x4 sc[4];
        #pragma unroll
        for (int kt = 0; kt < 4; kt++) {
            bf16x8 ka0 = *(const bf16x8*)&Ks[p][(kt * 16 + li) * LSTR + QD * 8];
            bf16x8 ka1 = *(const bf16x8*)&Ks[p][(kt * 16 + li) * LSTR + 32 + QD * 8];
            f32x4 c = (f32x4){0.f, 0.f, 0.f, 0.f};
            c = __builtin_amdgcn_mfma_f32_16x16x32_bf16(ka0, qb[0], c, 0, 0, 0);
            c = __builtin_amdgcn_mfma_f32_16x16x32_bf16(ka1, qb[1], c, 0, 0, 0);
            sc[kt] = c;
        }

        // ---- mask (only boundary/invalid tiles pay per-element cost) ----
        const int kbase = it * BC;
        if (kbase + BC > vl) {
            #pragma unroll
            for (int kt = 0; kt < 4; kt++)
                #pragma unroll
                for (int r = 0; r < 4; r++) {
                    int key = kbase + kt * 16 + QD * 4 + r;
                    if (key >= vl) sc[kt][r] = MASKED;
                }
        }

        // ---- online softmax in exp2 domain (row = query = li) ----
        float mt = -INFINITY;
        #pragma unroll
        for (int kt = 0; kt < 4; kt++)
            #pragma unroll
            for (int r = 0; r < 4; r++) mt = fmaxf(mt, sc[kt][r]);
        mt = fmaxf(mt, __shfl_xor(mt, 16, 64));
        mt = fmaxf(mt, __shfl_xor(mt, 32, 64));
        float mn = fmaxf(m_run, mt);
        float alpha = exp2f(m_run - mn);   // -inf on first tile -> 0
        m_run = mn;

        float ls = 0.f;
        #pragma unroll
        for (int kt = 0; kt < 4; kt++) {
            float p0 = exp2f(sc[kt][0] - mn);
            float p1 = exp2f(sc[kt][1] - mn);
            float p2 = exp2f(sc[kt][2] - mn);
            float p3 = exp2f(sc[kt][3] - mn);
            ls += (p0 + p1) + (p2 + p3);
            uint2 w;
            w.x = pack2_trunc(p0, p1);
            w.y = pack2_trunc(p2, p3);
            *(uint2*)&Ps[(wave * 16 + li) * LSTR + kt * 16 + QD * 4] = w;
        }
        ls += __shfl_xor(ls, 16, 64);
        ls += __shfl_xor(ls, 32, 64);
        l_run = l_run * alpha + ls;

        // rescale O accumulator rows (row = QD*4+r holds query QD*4+r)
        float a0 = __shfl(alpha, QD * 4 + 0, 64);
        float a1 = __shfl(alpha, QD * 4 + 1, 64);
        float a2 = __shfl(alpha, QD * 4 + 2, 64);
        float a3 = __shfl(alpha, QD * 4 + 3, 64);
        #pragma unroll
        for (int dt = 0; dt < 4; dt++) {
            acc[dt][0] *= a0; acc[dt][1] *= a1;
            acc[dt][2] *= a2; acc[dt][3] *= a3;
        }

        // ---- PV: O += P x V (same-wave LDS round-trip for P) ----
        bf16x8 pa0 = *(const bf16x8*)&Ps[(wave * 16 + li) * LSTR + QD * 8];
        bf16x8 pa1 = *(const bf16x8*)&Ps[(wave * 16 + li) * LSTR + 32 + QD * 8];
        #pragma unroll
        for (int dt = 0; dt < 4; dt++) {
            bf16x8 vb0 = *(const bf16x8*)&Vt[p][(dt * 16 + li) * LSTR + QD * 8];
            bf16x8 vb1 = *(const bf16x8*)&Vt[p][(dt * 16 + li) * LSTR + 32 + QD * 8];
            acc[dt] = __builtin_amdgcn_mfma_f32_16x16x32_bf16(pa0, vb0, acc[dt], 0, 0, 0);
            acc[dt] = __builtin_amdgcn_mfma_f32_16x16x32_bf16(pa1, vb1, acc[dt], 0, 0, 0);
        }

        // ---- overlapped staging of tile it+1 and prefetch of tile it+2 ----
        if (it + 1 < it_max) stage((it + 1) & 1);   // nobody reads buf 1-p this iter
        if (it + 2 < it_max) load_tile(it + 2);     // regs free after stage consumed them
        __syncthreads();   // ONE barrier per iteration
    }

    // ---- epilogue ----
    float invl = 1.0f / l_run;
    float i0 = __shfl(invl, QD * 4 + 0, 64);
    float i1 = __shfl(invl, QD * 4 + 1, 64);
    float i2 = __shfl(invl, QD * 4 + 2, 64);
    float i3 = __shfl(invl, QD * 4 + 3, 64);
    float* ob = out + boff + (size_t)q0 * DIM;
    const int rbase = wave * 16 + QD * 4;
    #pragma unroll
    for (int dt = 0; dt < 4; dt++) {
        int col = dt * 16 + li;
        ob[(size_t)(rbase + 0) * DIM + col] = acc[dt][0] * i0;
        ob[(size_t)(rbase + 1) * DIM + col] = acc[dt][1] * i1;
        ob[(size_t)(rbase + 2) * DIM + col] = acc[dt][2] * i2;
        ob[(size_t)(rbase + 3) * DIM + col] = acc[dt][3] * i3;
    }
}

extern "C" void kernel_launch(void* const* d_in, const int* in_sizes, int n_in,
                              void* d_out, int out_size, void* d_ws, size_t ws_size,
                              hipStream_t stream) {
    const float* q = (const float*)d_in[0];
    const float* k = (const float*)d_in[1];
    const float* v = (const float*)d_in[2];
    const int* valid_lens = (const int*)d_in[3];
    float* out = (float*)d_out;

    dim3 grid(BATCH * (SEQ / BQ));   // 64 x 16 = 1024 blocks
    dim3 block(256);
    attn_mfma_flash3<<<grid, block, 0, stream>>>(q, k, v, valid_lens, out);
}